// Round 1
// baseline (202.536 us; speedup 1.0000x reference)
//
#include <hip/hip_runtime.h>

#define NA 8     // attributes
#define NV 16    // values per attribute
#define NS (NA * NV)  // 128 segments

// ---------------------------------------------------------------------------
// Kernel 1: per-row sigmoid mean, LDS-aggregated per-block segment partials
// (fp32 sums + u32 counts), then one fp64/u32 global atomic per segment per
// block. fp32 block partials are ~30.0 max -> error negligible after fp64
// cross-block accumulation (need mean accuracy ~1e-6; we get ~1e-8).
// ---------------------------------------------------------------------------
__global__ __launch_bounds__(256) void attr_bias_accum(
    const float* __restrict__ preds,      // [B, 8]
    const int*   __restrict__ attrs,      // [B, 8]
    double*       __restrict__ g_sums,    // [128]
    unsigned int* __restrict__ g_counts,  // [128]
    int B)
{
    __shared__ float        s_sum[NS];
    __shared__ unsigned int s_cnt[NS];

    for (int i = threadIdx.x; i < NS; i += blockDim.x) {
        s_sum[i] = 0.0f;
        s_cnt[i] = 0u;
    }
    __syncthreads();

    const int stride = gridDim.x * blockDim.x;
    for (int r = blockIdx.x * blockDim.x + threadIdx.x; r < B; r += stride) {
        // 32B contiguous per row: two float4 loads
        const float4* p4 = (const float4*)(preds + (size_t)r * NA);
        float4 p0 = p4[0];
        float4 p1 = p4[1];

        float s = 1.0f / (1.0f + expf(-p0.x))
                + 1.0f / (1.0f + expf(-p0.y))
                + 1.0f / (1.0f + expf(-p0.z))
                + 1.0f / (1.0f + expf(-p0.w))
                + 1.0f / (1.0f + expf(-p1.x))
                + 1.0f / (1.0f + expf(-p1.y))
                + 1.0f / (1.0f + expf(-p1.z))
                + 1.0f / (1.0f + expf(-p1.w));
        float per_node = s * 0.125f;

        const int4* a4 = (const int4*)(attrs + (size_t)r * NA);
        int4 a0 = a4[0];
        int4 a1 = a4[1];

        atomicAdd(&s_sum[0 * NV + a0.x], per_node); atomicAdd(&s_cnt[0 * NV + a0.x], 1u);
        atomicAdd(&s_sum[1 * NV + a0.y], per_node); atomicAdd(&s_cnt[1 * NV + a0.y], 1u);
        atomicAdd(&s_sum[2 * NV + a0.z], per_node); atomicAdd(&s_cnt[2 * NV + a0.z], 1u);
        atomicAdd(&s_sum[3 * NV + a0.w], per_node); atomicAdd(&s_cnt[3 * NV + a0.w], 1u);
        atomicAdd(&s_sum[4 * NV + a1.x], per_node); atomicAdd(&s_cnt[4 * NV + a1.x], 1u);
        atomicAdd(&s_sum[5 * NV + a1.y], per_node); atomicAdd(&s_cnt[5 * NV + a1.y], 1u);
        atomicAdd(&s_sum[6 * NV + a1.z], per_node); atomicAdd(&s_cnt[6 * NV + a1.z], 1u);
        atomicAdd(&s_sum[7 * NV + a1.w], per_node); atomicAdd(&s_cnt[7 * NV + a1.w], 1u);
    }
    __syncthreads();

    for (int i = threadIdx.x; i < NS; i += blockDim.x) {
        unsigned int c = s_cnt[i];
        if (c) {
            atomicAdd(&g_sums[i], (double)s_sum[i]);   // HW global_atomic_add_f64
            atomicAdd(&g_counts[i], c);
        }
    }
}

// ---------------------------------------------------------------------------
// Kernel 2: 128 threads (one per segment). Compute means, pairwise squared
// diffs within each attribute (i<j, both present), reduce, write scalar.
// All fp64 — trivial cost, this kernel is ~2 us.
// ---------------------------------------------------------------------------
__global__ __launch_bounds__(128) void attr_bias_finalize(
    const double*       __restrict__ g_sums,
    const unsigned int* __restrict__ g_counts,
    float* __restrict__ out)
{
    __shared__ double s_mean[NS];
    __shared__ int    s_pres[NS];

    const int t = threadIdx.x;           // 0..127
    unsigned int c = g_counts[t];
    s_pres[t] = (c > 0u) ? 1 : 0;
    s_mean[t] = (c > 0u) ? (g_sums[t] / (double)c) : 0.0;
    __syncthreads();

    const int a = t >> 4;                // attribute
    const int i = t & (NV - 1);          // value index
    double loss = 0.0;
    int    ncmp = 0;
    if (s_pres[t]) {
        const double mi = s_mean[t];
        for (int j = i + 1; j < NV; ++j) {
            const int sj = a * NV + j;
            if (s_pres[sj]) {
                const double d = mi - s_mean[sj];
                loss += d * d;
                ncmp += 1;
            }
        }
    }

    // wave64 shuffle reduce, then combine the 2 waves via LDS
    for (int off = 32; off > 0; off >>= 1) {
        loss += __shfl_down(loss, off, 64);
        ncmp += __shfl_down(ncmp, off, 64);
    }
    __shared__ double w_loss[2];
    __shared__ int    w_ncmp[2];
    const int wave = t >> 6;
    if ((t & 63) == 0) {
        w_loss[wave] = loss;
        w_ncmp[wave] = ncmp;
    }
    __syncthreads();
    if (t == 0) {
        const double total = w_loss[0] + w_loss[1];
        const int    n     = w_ncmp[0] + w_ncmp[1];
        out[0] = (n > 0) ? (float)(total / (double)n) : 0.0f;
    }
}

extern "C" void kernel_launch(void* const* d_in, const int* in_sizes, int n_in,
                              void* d_out, int out_size, void* d_ws, size_t ws_size,
                              hipStream_t stream) {
    const float* preds = (const float*)d_in[0];
    const int*   attrs = (const int*)d_in[1];
    float*       out   = (float*)d_out;

    const int B = in_sizes[1] / NA;   // attr_vals is [B, 8]

    // workspace layout: [128 doubles sums][128 u32 counts]
    double*       g_sums   = (double*)d_ws;
    unsigned int* g_counts = (unsigned int*)(g_sums + NS);
    const size_t  ws_used  = NS * sizeof(double) + NS * sizeof(unsigned int);

    hipMemsetAsync(d_ws, 0, ws_used, stream);   // ws is re-poisoned to 0xAA each launch

    int blocks = (B + 255) / 256;
    if (blocks > 2048) blocks = 2048;           // 8 blocks/CU, grid-stride
    attr_bias_accum<<<blocks, 256, 0, stream>>>(preds, attrs, g_sums, g_counts, B);
    attr_bias_finalize<<<1, 128, 0, stream>>>(g_sums, g_counts, out);
}

// Round 2
// 148.943 us; speedup vs baseline: 1.3598x; 1.3598x over previous
//
#include <hip/hip_runtime.h>

#define NA 8
#define NV 16
#define NS (NA * NV)          // 128 segments
#define FIX_SHIFT 43
#define FIX_MASK ((1ULL << FIX_SHIFT) - 1)
#define FIX_SCALE 2147483648.0f   // 2^31

// ---------------------------------------------------------------------------
// K1: per-row sigmoid mean -> one packed ds_add_u64 per (row, attr).
// packed = (count=1) << 43  |  round(per_node * 2^31)
// Per-block bounds: rows/block <= 4096 -> sum field < 4096*2^31 < 2^43, ok;
// count < 2^21, ok. Epilogue: plain store of 128 packed partials, transposed
// [segment][block] so K2 reads coalesced. NO global atomics anywhere.
// ---------------------------------------------------------------------------
__global__ __launch_bounds__(256) void k1_accum(
    const float* __restrict__ preds,           // [B, 8]
    const int*   __restrict__ attrs,           // [B, 8]
    unsigned long long* __restrict__ partials, // [NS, nb]
    int B, int nb)
{
    __shared__ unsigned long long h[NS];
    for (int i = threadIdx.x; i < NS; i += 256) h[i] = 0ULL;
    __syncthreads();

    const int stride = nb * 256;
    for (int r = blockIdx.x * 256 + threadIdx.x; r < B; r += stride) {
        const float4* p4 = (const float4*)(preds + (size_t)r * NA);
        float4 p0 = p4[0];
        float4 p1 = p4[1];

        float s = __builtin_amdgcn_rcpf(1.0f + __expf(-p0.x))
                + __builtin_amdgcn_rcpf(1.0f + __expf(-p0.y))
                + __builtin_amdgcn_rcpf(1.0f + __expf(-p0.z))
                + __builtin_amdgcn_rcpf(1.0f + __expf(-p0.w))
                + __builtin_amdgcn_rcpf(1.0f + __expf(-p1.x))
                + __builtin_amdgcn_rcpf(1.0f + __expf(-p1.y))
                + __builtin_amdgcn_rcpf(1.0f + __expf(-p1.z))
                + __builtin_amdgcn_rcpf(1.0f + __expf(-p1.w));
        float per_node = s * 0.125f;               // in (0,1)
        unsigned int fixed = (unsigned int)(per_node * FIX_SCALE);  // < 2^31
        unsigned long long add = (1ULL << FIX_SHIFT) | (unsigned long long)fixed;

        const int4* a4 = (const int4*)(attrs + (size_t)r * NA);
        int4 a0 = a4[0];
        int4 a1 = a4[1];

        atomicAdd(&h[0 * NV + a0.x], add);
        atomicAdd(&h[1 * NV + a0.y], add);
        atomicAdd(&h[2 * NV + a0.z], add);
        atomicAdd(&h[3 * NV + a0.w], add);
        atomicAdd(&h[4 * NV + a1.x], add);
        atomicAdd(&h[5 * NV + a1.y], add);
        atomicAdd(&h[6 * NV + a1.z], add);
        atomicAdd(&h[7 * NV + a1.w], add);
    }
    __syncthreads();

    if (threadIdx.x < NS) {
        partials[(size_t)threadIdx.x * nb + blockIdx.x] = h[threadIdx.x];
    }
}

// ---------------------------------------------------------------------------
// K2: one block per segment. Coalesced read of nb packed partials, unpack,
// u64/u32 accumulate, wave+LDS reduce, fp64 mean.
// ---------------------------------------------------------------------------
__global__ __launch_bounds__(256) void k2_reduce(
    const unsigned long long* __restrict__ partials, // [NS, nb]
    double* __restrict__ means,                      // [NS]
    int*    __restrict__ pres,                       // [NS]
    int nb)
{
    const int s = blockIdx.x;
    unsigned long long sum = 0ULL;
    unsigned int cnt = 0u;
    for (int b = threadIdx.x; b < nb; b += 256) {
        unsigned long long p = partials[(size_t)s * nb + b];
        cnt += (unsigned int)(p >> FIX_SHIFT);
        sum += (p & FIX_MASK);
    }
    for (int off = 32; off > 0; off >>= 1) {
        sum += __shfl_down(sum, off, 64);
        cnt += __shfl_down(cnt, off, 64);
    }
    __shared__ unsigned long long ws_[4];
    __shared__ unsigned int wc_[4];
    const int wave = threadIdx.x >> 6;
    if ((threadIdx.x & 63) == 0) { ws_[wave] = sum; wc_[wave] = cnt; }
    __syncthreads();
    if (threadIdx.x == 0) {
        unsigned long long S = ws_[0] + ws_[1] + ws_[2] + ws_[3];
        unsigned int C = wc_[0] + wc_[1] + wc_[2] + wc_[3];
        means[s] = C ? ((double)S * (1.0 / (double)FIX_SCALE)) / (double)C : 0.0;
        pres[s]  = C ? 1 : 0;
    }
}

// ---------------------------------------------------------------------------
// K3: 1 block, 128 threads. Pairwise squared diffs of means within each
// attribute (i<j, both present), fp64 reduce, scalar out.
// ---------------------------------------------------------------------------
__global__ __launch_bounds__(128) void k3_finalize(
    const double* __restrict__ means,
    const int*    __restrict__ pres,
    float* __restrict__ out)
{
    __shared__ double s_mean[NS];
    __shared__ int    s_pres[NS];
    const int t = threadIdx.x;
    s_mean[t] = means[t];
    s_pres[t] = pres[t];
    __syncthreads();

    const int a = t >> 4;
    const int i = t & (NV - 1);
    double loss = 0.0;
    int    ncmp = 0;
    if (s_pres[t]) {
        const double mi = s_mean[t];
        for (int j = i + 1; j < NV; ++j) {
            const int sj = a * NV + j;
            if (s_pres[sj]) {
                const double d = mi - s_mean[sj];
                loss += d * d;
                ncmp += 1;
            }
        }
    }
    for (int off = 32; off > 0; off >>= 1) {
        loss += __shfl_down(loss, off, 64);
        ncmp += __shfl_down(ncmp, off, 64);
    }
    __shared__ double w_loss[2];
    __shared__ int    w_ncmp[2];
    const int wave = t >> 6;
    if ((t & 63) == 0) { w_loss[wave] = loss; w_ncmp[wave] = ncmp; }
    __syncthreads();
    if (t == 0) {
        const double total = w_loss[0] + w_loss[1];
        const int    n     = w_ncmp[0] + w_ncmp[1];
        out[0] = (n > 0) ? (float)(total / (double)n) : 0.0f;
    }
}

extern "C" void kernel_launch(void* const* d_in, const int* in_sizes, int n_in,
                              void* d_out, int out_size, void* d_ws, size_t ws_size,
                              hipStream_t stream) {
    const float* preds = (const float*)d_in[0];
    const int*   attrs = (const int*)d_in[1];
    float*       out   = (float*)d_out;

    const int B = in_sizes[1] / NA;

    // Pick nb (K1 grid) by available workspace; 1024 preferred (4 blocks/CU).
    // Tail region for means (128 f64) + pres (128 i32).
    const size_t tail = NS * sizeof(double) + NS * sizeof(int);
    int nb = 1024;
    if (ws_size < (size_t)NS * 1024 * sizeof(unsigned long long) + tail) nb = 512;

    unsigned long long* partials = (unsigned long long*)d_ws;
    double* means = (double*)((char*)d_ws + (size_t)NS * nb * sizeof(unsigned long long));
    int*    pres  = (int*)(means + NS);

    k1_accum<<<nb, 256, 0, stream>>>(preds, attrs, partials, B, nb);
    k2_reduce<<<NS, 256, 0, stream>>>(partials, means, pres, nb);
    k3_finalize<<<1, 128, 0, stream>>>(means, pres, out);
}